// Round 8
// baseline (769.509 us; speedup 1.0000x reference)
//
#include <hip/hip_runtime.h>
#include <math.h>
#include <type_traits>

#define IMG_H 512
#define IMG_W 512
#define NIMG 64
#define TH 32
#define HALO 5
#define KSIZE 11
#define NROWS (TH + 2*HALO)   // 42 real input rows; padded to 44 steps
#define LUNITS 70             // 70 float4 units = 140 staged cols per wave

// 2 output columns per lane. Staging: interleaved float4 {p0,g0,p1,g1} units
// in LDS, XOR-swizzled on the 16B-unit index (u ^= (u>>3)&1, applied on BOTH
// write and read) so the 32B/lane stride spreads across all 32 banks.
// Per step per wave: 7 ds_read_b128 + 2 ds_write_b128 for 128 outputs —
// vs 26 b32 DS ops per 64 outputs in the round-2/7 structure (the measured
// ~5.8cyc/DS-instr issue rate made that the bottleneck: 26*5.8=151 cyc/step
// matches the observed 175). Vertical 11-row ring now 110 VGPR (2 cols) ->
// launch_bounds(256,3) (~170 VGPR budget) to stay off the spill cliff.
__global__ __launch_bounds__(256, 3)
void ssim_main(const float* __restrict__ pred, const float* __restrict__ gt,
               float* __restrict__ partial) {
    __shared__ float4 lds[4 * LUNITS];
    __shared__ float wsum[4];

    const int tid  = threadIdx.x;
    const int wv   = tid >> 6;
    const int lane = tid & 63;
    const int bid  = blockIdx.x;
    const int img  = bid >> 4;            // 16 blocks per image
    const int r0   = (bid & 15) * TH;     // 16 row chunks of 32
    const int c0   = wv * 128;            // wave's first output col (4 strips)

    // Gaussian 11-tap, sigma = 11/6, normalized (symmetric: W[k]=W[10-k]).
    constexpr float W[6] = {0.0052913f, 0.0201843f, 0.0571853f,
                            0.1203038f, 0.1879737f, 0.2181237f};

    const float* pimg = pred + (size_t)img * (IMG_H * IMG_W);
    const float* gimg = gt   + (size_t)img * (IMG_H * IMG_W);

    // staged col range: c0-6 .. c0+133 (140 cols, even-aligned pairs so no
    // pair straddles an image edge). main: lanes 0..63 stage cols cm,cm+1;
    // tail: lanes 0..5 stage cols ct,ct+1.
    const int  cm  = c0 - 6 + 2 * lane;
    const int  ct  = c0 + 122 + 2 * lane;
    const bool mok = (cm >= 0) && (cm < IMG_W);
    const bool tok = (lane < 6) && (ct < IMG_W);
    const int  r_in0 = r0 - HALO;
    const int  rlast = r_in0 + NROWS - 1;

    float2 pm, gm, pt, gt2;               // staged regs (next row)
    auto load_row = [&](int rr) {
        const bool rok = (rr >= 0) && (rr < IMG_H) && (rr <= rlast);
        const float* prow = pimg + (size_t)rr * IMG_W;
        const float* grow = gimg + (size_t)rr * IMG_W;
        const float2 z = make_float2(0.f, 0.f);
        pm  = (rok && mok) ? *(const float2*)(prow + cm) : z;
        gm  = (rok && mok) ? *(const float2*)(grow + cm) : z;
        pt  = (rok && tok) ? *(const float2*)(prow + ct) : z;
        gt2 = (rok && tok) ? *(const float2*)(grow + ct) : z;
    };
    load_row(r_in0);

    const int ub = wv * LUNITS;
    auto swz = [](int u) { return u ^ ((u >> 3) & 1); };
    const int wrm = ub + swz(lane);        // main write unit
    const int wrt = ub + swz(64 + lane);   // tail write unit (lanes 0..5)
    int rdx[7];                            // read units lane..lane+6
    #pragma unroll
    for (int j = 0; j < 7; ++j) rdx[j] = ub + swz(lane + j);

    // vertical ring: 5 fields x 11 rows x 2 cols, statically indexed
    float2 rp[KSIZE], rg[KSIZE], rpp[KSIZE], rgg[KSIZE], rpg[KSIZE];
    float lsum = 0.f;
    const float C1v = 1e-4f;   // 0.01^2
    const float C2v = 9e-4f;   // 0.03^2

    auto step = [&](int i, auto jc) {
        constexpr int jj = decltype(jc)::value;   // ring slot, static

        __builtin_amdgcn_wave_barrier();   // prev row's reads before writes
        lds[wrm] = make_float4(pm.x, gm.x, pm.y, gm.y);
        if (lane < 6) lds[wrt] = make_float4(pt.x, gt2.x, pt.y, gt2.y);
        load_row(r_in0 + i + 1);           // prefetch stays in flight
        __builtin_amdgcn_wave_barrier();   // writes before this row's reads

        float4 rv[7];                      // cols c0-6+2*lane + [0..13]
        #pragma unroll
        for (int j = 0; j < 7; ++j) rv[j] = lds[rdx[j]];

        // horizontal 11-tap for both cols; col0 tap k uses offset m=k+1,
        // col1 uses m=k+2 within the 14-col window (rv[m>>1], xz=p, yw=g)
        float hp0=0.f,hg0=0.f,hpp0=0.f,hgg0=0.f,hpg0=0.f;
        float hp1=0.f,hg1=0.f,hpp1=0.f,hgg1=0.f,hpg1=0.f;
        #pragma unroll
        for (int k = 0; k < KSIZE; ++k) {
            const float w = W[k < 6 ? k : 10 - k];
            const int m0 = k + 1, m1 = k + 2;
            const float p0 = (m0 & 1) ? rv[m0 >> 1].z : rv[m0 >> 1].x;
            const float g0 = (m0 & 1) ? rv[m0 >> 1].w : rv[m0 >> 1].y;
            const float p1 = (m1 & 1) ? rv[m1 >> 1].z : rv[m1 >> 1].x;
            const float g1 = (m1 & 1) ? rv[m1 >> 1].w : rv[m1 >> 1].y;
            float t0 = w * p0, u0 = w * g0;
            hp0 += t0; hg0 += u0;
            hpp0 = fmaf(t0, p0, hpp0);
            hgg0 = fmaf(u0, g0, hgg0);
            hpg0 = fmaf(t0, g0, hpg0);
            float t1 = w * p1, u1 = w * g1;
            hp1 += t1; hg1 += u1;
            hpp1 = fmaf(t1, p1, hpp1);
            hgg1 = fmaf(u1, g1, hgg1);
            hpg1 = fmaf(t1, g1, hpg1);
        }
        rp[jj]  = make_float2(hp0, hp1);
        rg[jj]  = make_float2(hg0, hg1);
        rpp[jj] = make_float2(hpp0, hpp1);
        rgg[jj] = make_float2(hgg0, hgg1);
        rpg[jj] = make_float2(hpg0, hpg1);

        // vertical 11-tap + SSIM once ring is full (output row = r_in0+i-5)
        if (i >= 10 && i < NROWS) {
            float m1x=0.f,m1y=0.f,m2x=0.f,m2y=0.f;
            float vpx=0.f,vpy=0.f,vgx=0.f,vgy=0.f,vcx=0.f,vcy=0.f;
            #pragma unroll
            for (int d = 0; d < KSIZE; ++d) {
                const int slot = (jj + 1 + d) % KSIZE;   // constant-folded
                const float w = W[d < 6 ? d : 10 - d];
                m1x = fmaf(w, rp[slot].x,  m1x);  m1y = fmaf(w, rp[slot].y,  m1y);
                m2x = fmaf(w, rg[slot].x,  m2x);  m2y = fmaf(w, rg[slot].y,  m2y);
                vpx = fmaf(w, rpp[slot].x, vpx);  vpy = fmaf(w, rpp[slot].y, vpy);
                vgx = fmaf(w, rgg[slot].x, vgx);  vgy = fmaf(w, rgg[slot].y, vgy);
                vcx = fmaf(w, rpg[slot].x, vcx);  vcy = fmaf(w, rpg[slot].y, vcy);
            }
            {   // col0
                const float m11 = m1x*m1x, m22 = m2x*m2x, m12 = m1x*m2x;
                const float s1 = vpx - m11, s2 = vgx - m22, s12 = vcx - m12;
                const float num = fmaf(2.f, m12, C1v) * fmaf(2.f, s12, C2v);
                const float den = (m11 + m22 + C1v) * (s1 + s2 + C2v);
                lsum += num * __builtin_amdgcn_rcpf(den);
            }
            {   // col1
                const float m11 = m1y*m1y, m22 = m2y*m2y, m12 = m1y*m2y;
                const float s1 = vpy - m11, s2 = vgy - m22, s12 = vcy - m12;
                const float num = fmaf(2.f, m12, C1v) * fmaf(2.f, s12, C2v);
                const float den = (m11 + m22 + C1v) * (s1 + s2 + C2v);
                lsum += num * __builtin_amdgcn_rcpf(den);
            }
        }
    };

    #pragma unroll 1
    for (int ob = 0; ob < 4; ++ob) {
        const int base = ob * KSIZE;
        step(base + 0,  std::integral_constant<int, 0>{});
        step(base + 1,  std::integral_constant<int, 1>{});
        step(base + 2,  std::integral_constant<int, 2>{});
        step(base + 3,  std::integral_constant<int, 3>{});
        step(base + 4,  std::integral_constant<int, 4>{});
        step(base + 5,  std::integral_constant<int, 5>{});
        step(base + 6,  std::integral_constant<int, 6>{});
        step(base + 7,  std::integral_constant<int, 7>{});
        step(base + 8,  std::integral_constant<int, 8>{});
        step(base + 9,  std::integral_constant<int, 9>{});
        step(base + 10, std::integral_constant<int, 10>{});
    }

    // per-wave shuffle reduction, one barrier outside hot loop, one atomic
    #pragma unroll
    for (int off = 32; off > 0; off >>= 1) lsum += __shfl_down(lsum, off);
    if (lane == 0) wsum[wv] = lsum;
    __syncthreads();
    if (tid == 0) {
        float b = wsum[0] + wsum[1] + wsum[2] + wsum[3];
        atomicAdd(partial, b);
    }
}

__global__ void ssim_final(const float* __restrict__ partial,
                           float* __restrict__ out) {
    out[0] = 1.f - partial[0] * (1.f / (float)((size_t)NIMG * IMG_H * IMG_W));
}

extern "C" void kernel_launch(void* const* d_in, const int* in_sizes, int n_in,
                              void* d_out, int out_size, void* d_ws, size_t ws_size,
                              hipStream_t stream) {
    const float* pred = (const float*)d_in[0];
    const float* gt   = (const float*)d_in[1];
    float* out = (float*)d_out;
    float* ws  = (float*)d_ws;

    hipMemsetAsync(ws, 0, sizeof(float), stream);

    const int nblocks = NIMG * 16;   // 64 imgs * 16 row chunks (4 col strips = 4 waves)
    ssim_main<<<nblocks, 256, 0, stream>>>(pred, gt, ws);
    ssim_final<<<1, 1, 0, stream>>>(ws, out);
}

// Round 9
// 225.418 us; speedup vs baseline: 3.4137x; 3.4137x over previous
//
#include <hip/hip_runtime.h>
#include <math.h>
#include <type_traits>

#define IMG_H 512
#define IMG_W 512
#define NIMG 64
#define TH 32        // output rows per wave tile
#define HALO 5
#define KSIZE 11
#define LROW 74      // 64 output cols + 2*5 halo staged per wave
#define NROWS (TH + 2*HALO)   // 42 input rows per tile

// Round-3 structure (float2 {p,g} LDS staging: 11 ds_read_b64 + 2 ds_write_b64
// per step = 13 DS ops vs 26 b32 ops — the kernel is DS-instruction-issue
// bound at ~5.8cyc/op). Fix for the round-3/6/8 spills: empirically this
// toolchain caps per-thread VGPRs at 256/min_waves_per_EU (w=8->32, w=4->64,
// w=3->84 observed). The 55-reg ring + float2 temps needs ~80-95, so w=2
// (cap 128). Hardware occupancy then follows actual VGPR use
// (floor(512/VGPR) waves/SIMD), not the compiler cap.
__global__ __launch_bounds__(256, 2)
void ssim_main(const float* __restrict__ pred, const float* __restrict__ gt,
               float* __restrict__ partial) {
    __shared__ float2 spg[4][LROW];
    __shared__ float wsum[4];

    const int tid  = threadIdx.x;
    const int wv   = tid >> 6;
    const int lane = tid & 63;
    const int bid  = blockIdx.x;
    const int img  = bid >> 5;            // 32 blocks per image
    const int rem  = bid & 31;
    const int c0   = (rem & 1) * 256 + wv * 64;  // 8 col tiles of 64
    const int r0   = (rem >> 1) * TH;            // 16 row chunks of 32

    // Gaussian 11-tap, sigma = 11/6, normalized (symmetric: W[k]=W[10-k]).
    constexpr float W[6] = {0.0052913f, 0.0201843f, 0.0571853f,
                            0.1203038f, 0.1879737f, 0.2181237f};

    const float* pimg = pred + (size_t)img * (IMG_H * IMG_W);
    const float* gimg = gt   + (size_t)img * (IMG_H * IMG_W);

    const int  cs0  = c0 - HALO + lane;      // staged col for this lane
    const int  cs1  = cs0 + 64;              // tail col (lanes 0..9)
    const bool has2 = lane < (LROW - 64);
    const bool c0ok = (cs0 >= 0) && (cs0 < IMG_W);
    const bool c1ok = has2 && (cs1 < IMG_W);
    const int  r_in0 = r0 - HALO;
    const int  rlast = r_in0 + NROWS - 1;

    float stp0, stp1, stg0, stg1;            // staged regs (next row)
    auto load_row = [&](int rr) {
        const bool rok = (rr >= 0) && (rr < IMG_H) && (rr <= rlast);
        const float* prow = pimg + (size_t)rr * IMG_W;
        const float* grow = gimg + (size_t)rr * IMG_W;
        stp0 = (rok && c0ok) ? prow[cs0] : 0.f;
        stg0 = (rok && c0ok) ? grow[cs0] : 0.f;
        stp1 = (rok && c1ok) ? prow[cs1] : 0.f;
        stg1 = (rok && c1ok) ? grow[cs1] : 0.f;
    };
    load_row(r_in0);

    // vertical ring: 5 fields x 11 rows, statically indexed
    float rp[KSIZE], rg[KSIZE], rpp[KSIZE], rgg[KSIZE], rpg[KSIZE];
    float lsum = 0.f;
    const float C1v = 1e-4f;   // 0.01^2
    const float C2v = 9e-4f;   // 0.03^2

    float2* sw = &spg[wv][0];

    auto step = [&](int i, auto jc) {
        constexpr int jj = decltype(jc)::value;   // ring slot = i mod 11
        const int r = r_in0 + i;

        __builtin_amdgcn_wave_barrier();   // prev row's reads before writes
        sw[lane] = make_float2(stp0, stg0);
        if (has2) sw[lane + 64] = make_float2(stp1, stg1);
        load_row(r + 1);                   // prefetch stays in flight
        __builtin_amdgcn_wave_barrier();   // writes before this row's reads

        // horizontal 11-tap conv, symmetric pairs, float2 reads (b64,
        // adjacent-tap pairs mergeable to ds_read2_b64)
        float2 vc = sw[lane + 5];
        float t1 = W[5] * vc.x;
        float t2 = W[5] * vc.y;
        float hp = t1, hg = t2;
        float hpp = t1 * vc.x;
        float hgg = t2 * vc.y;
        float hpg = t1 * vc.y;
        #pragma unroll
        for (int k = 0; k < 5; ++k) {
            float2 vA = sw[lane + k];
            float2 vB = sw[lane + 10 - k];
            const float w = W[k];
            hp  = fmaf(w, vA.x + vB.x, hp);
            hg  = fmaf(w, vA.y + vB.y, hg);
            hpp = fmaf(w, fmaf(vA.x, vA.x, vB.x * vB.x), hpp);
            hgg = fmaf(w, fmaf(vA.y, vA.y, vB.y * vB.y), hgg);
            hpg = fmaf(w, fmaf(vA.x, vA.y, vB.x * vB.y), hpg);
        }
        rp[jj] = hp; rg[jj] = hg; rpp[jj] = hpp; rgg[jj] = hgg; rpg[jj] = hpg;

        // vertical 11-tap + SSIM once ring is full (output row = r-5)
        if (i >= 10 && i < NROWS) {
            float mu1 = 0.f, mu2 = 0.f, svpp = 0.f, svgg = 0.f, svpg = 0.f;
            #pragma unroll
            for (int d = 0; d < KSIZE; ++d) {
                const int slot = (jj + 1 + d) % KSIZE;   // constant-folded
                const float w = W[d < 6 ? d : 10 - d];
                mu1  = fmaf(w, rp[slot],  mu1);
                mu2  = fmaf(w, rg[slot],  mu2);
                svpp = fmaf(w, rpp[slot], svpp);
                svgg = fmaf(w, rgg[slot], svgg);
                svpg = fmaf(w, rpg[slot], svpg);
            }
            const float m11 = mu1 * mu1;
            const float m22 = mu2 * mu2;
            const float m12 = mu1 * mu2;
            const float s1  = svpp - m11;
            const float s2  = svgg - m22;
            const float s12 = svpg - m12;
            const float num = fmaf(2.f, m12, C1v) * fmaf(2.f, s12, C2v);
            const float den = (m11 + m22 + C1v) * (s1 + s2 + C2v);
            lsum += num * __builtin_amdgcn_rcpf(den);
        }
    };

    #define S_(I, J) step((I), std::integral_constant<int, (J)>{})
    #pragma unroll 1
    for (int ob = 0; ob < 3; ++ob) {
        const int b = ob * KSIZE;
        S_(b + 0, 0);  S_(b + 1, 1);  S_(b + 2, 2);  S_(b + 3, 3);
        S_(b + 4, 4);  S_(b + 5, 5);  S_(b + 6, 6);  S_(b + 7, 7);
        S_(b + 8, 8);  S_(b + 9, 9);  S_(b + 10, 10);
    }
    // epilogue: i = 33..41, ring slots 0..8 (33 % 11 == 0)
    S_(33, 0); S_(34, 1); S_(35, 2); S_(36, 3); S_(37, 4);
    S_(38, 5); S_(39, 6); S_(40, 7); S_(41, 8);
    #undef S_

    // per-wave shuffle reduction, one barrier outside the hot loop, one atomic
    #pragma unroll
    for (int off = 32; off > 0; off >>= 1) lsum += __shfl_down(lsum, off);
    if (lane == 0) wsum[wv] = lsum;
    __syncthreads();
    if (tid == 0) {
        float b = wsum[0] + wsum[1] + wsum[2] + wsum[3];
        atomicAdd(partial, b);
    }
}

__global__ void ssim_final(const float* __restrict__ partial,
                           float* __restrict__ out) {
    out[0] = 1.f - partial[0] * (1.f / (float)((size_t)NIMG * IMG_H * IMG_W));
}

extern "C" void kernel_launch(void* const* d_in, const int* in_sizes, int n_in,
                              void* d_out, int out_size, void* d_ws, size_t ws_size,
                              hipStream_t stream) {
    const float* pred = (const float*)d_in[0];
    const float* gt   = (const float*)d_in[1];
    float* out = (float*)d_out;
    float* ws  = (float*)d_ws;

    hipMemsetAsync(ws, 0, sizeof(float), stream);

    const int nblocks = NIMG * 32;   // 64 imgs * 8 col tiles * 16 row chunks
    ssim_main<<<nblocks, 256, 0, stream>>>(pred, gt, ws);
    ssim_final<<<1, 1, 0, stream>>>(ws, out);
}